// Round 1
// 124.577 us; speedup vs baseline: 1.1124x; 1.1124x over previous
//
#include <hip/hip_runtime.h>
#include <hip/hip_bf16.h>

constexpr int kB = 16;
constexpr int kN = 2048;
constexpr int kH = 64;
constexpr int kF = 6;

typedef short s16x8 __attribute__((ext_vector_type(8)));
typedef float f32x4 __attribute__((ext_vector_type(4)));

__device__ __forceinline__ unsigned short f2bf(float f) {
  __hip_bfloat16 h = __float2bfloat16(f);
  unsigned short u;
  __builtin_memcpy(&u, &h, 2);
  return u;
}

__device__ __forceinline__ float bf2f(unsigned short u) {
  unsigned int b = ((unsigned int)u) << 16;
  float f;
  __builtin_memcpy(&f, &b, 4);
  return f;
}

__device__ __forceinline__ float eluf(float x) {
  return x > 0.0f ? x : __expf(x) - 1.0f;
}

__device__ __forceinline__ unsigned int pack8(uint4 a, uint4 b) {
  unsigned int t1 = (a.y << 1) + a.x;
  unsigned int t2 = (a.w << 1) + a.z;
  unsigned int n0 = (t2 << 2) + t1;
  unsigned int u1 = (b.y << 1) + b.x;
  unsigned int u2 = (b.w << 1) + b.z;
  unsigned int n1 = (u2 << 2) + u1;
  return (n1 << 4) + n0;
}

// ---------------------------------------------------------------- layer1 embed
__global__ __launch_bounds__(256) void k_embed(
    const float* __restrict__ x, const float* __restrict__ W,
    const float* __restrict__ asrc, const float* __restrict__ adst,
    const float* __restrict__ mask,
    float* __restrict__ hf, unsigned short* __restrict__ hT,
    unsigned int* __restrict__ uvpk, float* __restrict__ Rr,
    float* __restrict__ sumh) {
  __shared__ float lh[64][65];
  __shared__ float psd[2][4][64];
  const int r0 = blockIdx.x * 64;
  const int b = r0 >> 11;
  const int i0 = r0 & (kN - 1);
  const int t = threadIdx.x;
  const int k = t & 63;
  const int w = t >> 6;
  if (blockIdx.x == 0) {
#pragma unroll
    for (int i = 0; i < 4; ++i) sumh[t + 256 * i] = 0.0f;
  }
  for (int it = 0; it < 16; ++it) {
    const int rl = w * 16 + it;
    const int row = r0 + rl;
    float h = 0.0f;
#pragma unroll
    for (int f = 0; f < kF; ++f) h = fmaf(x[(size_t)row * kF + f], W[f * kH + k], h);
    lh[rl][k] = h;
    hf[(size_t)row * kH + k] = h;
  }
  __syncthreads();
  float sp = 0.0f, dp = 0.0f;
#pragma unroll
  for (int kk = 0; kk < 16; ++kk) {
    const int k2 = w * 16 + kk;
    const float hv = lh[k][k2];
    sp = fmaf(hv, asrc[k2], sp);
    dp = fmaf(hv, adst[k2], dp);
  }
  psd[0][w][k] = sp;
  psd[1][w][k] = dp;
  __syncthreads();
  if (t < 64) {
    const float s = psd[0][0][t] + psd[0][1][t] + psd[0][2][t] + psd[0][3][t];
    const float d = psd[1][0][t] + psd[1][1][t] + psd[1][2][t] + psd[1][3][t];
    const int row = r0 + t;
    const bool mv = mask[row] != 0.0f;
    const float u = mv ? __expf(d) : 0.0f;
    const float v = mv ? __expf(0.2f * d) : 0.0f;
    uvpk[row] = ((unsigned int)f2bf(u) << 16) | f2bf(v);
    Rr[row] = __expf(-0.8f * s);
  }
  const size_t tb = (size_t)b * kN * kH + (size_t)(i0 >> 5) * 2048;
  for (int it = 0; it < 16; ++it) {
    const int kk = w * 16 + it;
    hT[tb + (size_t)(k >> 5) * 2048 + kk * 32 + (k & 31)] = f2bf(lh[k][kk]);
  }
}

// ---------------------------------------------------------------- layer2 embed (reads final h1)
// 64x64x64 matmul done with split-bf16 MFMA: h = hi+lo, W = Whi+Wlo,
// h@W ~= hi@Whi + hi@Wlo + lo@Whi  (dropped lo@Wlo term ~2^-18 relative).
__global__ __launch_bounds__(256) void k_embed2(
    const float* __restrict__ hin, const float* __restrict__ W,
    const float* __restrict__ asrc, const float* __restrict__ adst,
    const float* __restrict__ mask,
    float* __restrict__ hf, unsigned short* __restrict__ hT,
    unsigned int* __restrict__ uvpk, float* __restrict__ Rr) {
  __shared__ unsigned short Ahi[64][72], Alo[64][72];    // h rows, bf16 hi/lo
  __shared__ unsigned short WThi[64][72], WTlo[64][72];  // W transposed [col][k]
  __shared__ float lh[64][65];
  __shared__ float psd[2][4][64];
  const int r0 = blockIdx.x * 64;
  const int b = r0 >> 11;
  const int i0 = r0 & (kN - 1);
  const int t = threadIdx.x;
  const int k = t & 63;
  const int w = t >> 6;
  const int l = t & 63;
  const int r16 = l & 15;
  const int g4 = l >> 4;

  // stage h tile (rows) and W (transposed) as bf16 hi/lo pairs
  for (int it = 0; it < 16; ++it) {
    const int rl = w * 16 + it;
    const float hv = hin[(size_t)(r0 + rl) * kH + k];
    const unsigned short hh = f2bf(hv);
    const unsigned short hl = f2bf(hv - bf2f(hh));
    Ahi[rl][k] = hh;
    Alo[rl][k] = hl;
    const float wv = W[rl * kH + k];  // W[k-dim = rl][col = k]
    const unsigned short wh = f2bf(wv);
    const unsigned short wl = f2bf(wv - bf2f(wh));
    WThi[k][rl] = wh;
    WTlo[k][rl] = wl;
  }
  __syncthreads();

  // wave w computes rows [w*16, w*16+16) x all 64 cols
  f32x4 acc0 = {0.f, 0.f, 0.f, 0.f}, acc1 = {0.f, 0.f, 0.f, 0.f};
  f32x4 acc2 = {0.f, 0.f, 0.f, 0.f}, acc3 = {0.f, 0.f, 0.f, 0.f};
#pragma unroll
  for (int ks = 0; ks < 2; ++ks) {
    const int kof = ks * 32 + g4 * 8;
    const s16x8 ahi = *(const s16x8*)&Ahi[w * 16 + r16][kof];
    const s16x8 alo = *(const s16x8*)&Alo[w * 16 + r16][kof];
    {
      const s16x8 bhi = *(const s16x8*)&WThi[0 * 16 + r16][kof];
      const s16x8 blo = *(const s16x8*)&WTlo[0 * 16 + r16][kof];
      acc0 = __builtin_amdgcn_mfma_f32_16x16x32_bf16(ahi, bhi, acc0, 0, 0, 0);
      acc0 = __builtin_amdgcn_mfma_f32_16x16x32_bf16(alo, bhi, acc0, 0, 0, 0);
      acc0 = __builtin_amdgcn_mfma_f32_16x16x32_bf16(ahi, blo, acc0, 0, 0, 0);
    }
    {
      const s16x8 bhi = *(const s16x8*)&WThi[1 * 16 + r16][kof];
      const s16x8 blo = *(const s16x8*)&WTlo[1 * 16 + r16][kof];
      acc1 = __builtin_amdgcn_mfma_f32_16x16x32_bf16(ahi, bhi, acc1, 0, 0, 0);
      acc1 = __builtin_amdgcn_mfma_f32_16x16x32_bf16(alo, bhi, acc1, 0, 0, 0);
      acc1 = __builtin_amdgcn_mfma_f32_16x16x32_bf16(ahi, blo, acc1, 0, 0, 0);
    }
    {
      const s16x8 bhi = *(const s16x8*)&WThi[2 * 16 + r16][kof];
      const s16x8 blo = *(const s16x8*)&WTlo[2 * 16 + r16][kof];
      acc2 = __builtin_amdgcn_mfma_f32_16x16x32_bf16(ahi, bhi, acc2, 0, 0, 0);
      acc2 = __builtin_amdgcn_mfma_f32_16x16x32_bf16(alo, bhi, acc2, 0, 0, 0);
      acc2 = __builtin_amdgcn_mfma_f32_16x16x32_bf16(ahi, blo, acc2, 0, 0, 0);
    }
    {
      const s16x8 bhi = *(const s16x8*)&WThi[3 * 16 + r16][kof];
      const s16x8 blo = *(const s16x8*)&WTlo[3 * 16 + r16][kof];
      acc3 = __builtin_amdgcn_mfma_f32_16x16x32_bf16(ahi, bhi, acc3, 0, 0, 0);
      acc3 = __builtin_amdgcn_mfma_f32_16x16x32_bf16(alo, bhi, acc3, 0, 0, 0);
      acc3 = __builtin_amdgcn_mfma_f32_16x16x32_bf16(ahi, blo, acc3, 0, 0, 0);
    }
  }

  // C layout: col = lane&15 (+16*n), row = (lane>>4)*4 + q (+16*w)
#pragma unroll
  for (int q = 0; q < 4; ++q) {
    const int rl = w * 16 + g4 * 4 + q;
    lh[rl][0 * 16 + r16] = acc0[q];
    lh[rl][1 * 16 + r16] = acc1[q];
    lh[rl][2 * 16 + r16] = acc2[q];
    lh[rl][3 * 16 + r16] = acc3[q];
    const size_t rowg = (size_t)(r0 + rl) * kH;
    hf[rowg + 0 * 16 + r16] = acc0[q];
    hf[rowg + 1 * 16 + r16] = acc1[q];
    hf[rowg + 2 * 16 + r16] = acc2[q];
    hf[rowg + 3 * 16 + r16] = acc3[q];
  }
  __syncthreads();

  float sp = 0.0f, dp = 0.0f;
#pragma unroll
  for (int kk = 0; kk < 16; ++kk) {
    const int k2 = w * 16 + kk;
    const float hv = lh[k][k2];
    sp = fmaf(hv, asrc[k2], sp);
    dp = fmaf(hv, adst[k2], dp);
  }
  psd[0][w][k] = sp;
  psd[1][w][k] = dp;
  __syncthreads();
  if (t < 64) {
    const float s = psd[0][0][t] + psd[0][1][t] + psd[0][2][t] + psd[0][3][t];
    const float d = psd[1][0][t] + psd[1][1][t] + psd[1][2][t] + psd[1][3][t];
    const int row = r0 + t;
    const bool mv = mask[row] != 0.0f;
    const float u = mv ? __expf(d) : 0.0f;
    const float v = mv ? __expf(0.2f * d) : 0.0f;
    uvpk[row] = ((unsigned int)f2bf(u) << 16) | f2bf(v);
    Rr[row] = __expf(-0.8f * s);
  }
  const size_t tb = (size_t)b * kN * kH + (size_t)(i0 >> 5) * 2048;
  for (int it = 0; it < 16; ++it) {
    const int kk = w * 16 + it;
    hT[tb + (size_t)(k >> 5) * 2048 + kk * 32 + (k & 31)] = f2bf(lh[k][kk]);
  }
}

// ---------------------------------------------------------------- fused GAT attention
// Block = 32 full rows. 4 waves: (row-tile rt = wv&1) x (j-half hf = wv>>1).
// Conflict-free staging: thread t publishes ONE 16B block per half-tile at t*16.
// Loop barrier is raw s_barrier + lgkmcnt(0) only (T4): global prefetch loads
// stay in flight across the barrier; compiler emits counted vmcnt at publish.
template <bool PACK, bool TAIL>
__global__ __launch_bounds__(256) void k_attn(
    const int* __restrict__ adj, unsigned int* __restrict__ bits,
    const unsigned short* __restrict__ hT,
    const unsigned int* __restrict__ uvpk, const float* __restrict__ Rr,
    const float* __restrict__ hres, const float* __restrict__ mask,
    float* __restrict__ hout,
    const float* __restrict__ aw1, const float* __restrict__ ab1,
    const float* __restrict__ aw2, const float* __restrict__ ab2,
    float* __restrict__ logits, float* __restrict__ sumh) {
  __shared__ __align__(16) char smem[32896];
  unsigned int* uvl = (unsigned int*)smem;
  unsigned int* blw = (unsigned int*)(smem + 8192);
  unsigned short* hbase = (unsigned short*)(smem + 16512);

  const int bid0 = blockIdx.x;
  const int swz = (bid0 & 7) * 128 + (bid0 >> 3);  // 2 batches per XCD
  const int b = swz >> 6;
  const int rb = swz & 63;
  const int row0 = rb * 32;

  const int t = threadIdx.x;
  const int wv = t >> 6;
  const int l = t & 63;
  const int r = l & 15;
  const int g = l >> 4;
  const int rt = wv & 1;
  const int hf2 = wv >> 1;
  const int rloc = rt * 16 + r;

  // stage uv (full row, 8KB)
  {
    const uint4* src = (const uint4*)(uvpk + (size_t)b * kN);
    ((uint4*)uvl)[t] = src[t];
    ((uint4*)uvl)[t + 256] = src[t + 256];
  }

  // hT staging: thread t owns shorts [t*8, t*8+8) of each half-tile (conflict-free)
  const unsigned short* hTb = hT + (size_t)b * kN * kH;
  {
    *(uint4*)(hbase + 0 * 2048 + t * 8) = *(const uint4*)(hTb + t * 8);                     // half0 tile0
    *(uint4*)(hbase + 1 * 2048 + t * 8) = *(const uint4*)(hTb + (size_t)32 * 2048 + t * 8); // half1 tile0
  }
  uint4 hc0 = *(const uint4*)(hTb + (size_t)1 * 2048 + t * 8);
  uint4 hc1 = *(const uint4*)(hTb + (size_t)33 * 2048 + t * 8);
  uint4 hn0 = {}, hn1 = {};

  // bits: PACK = JIT from adj (2-deep pipeline); else stage all from global
  const int brow = t >> 3;
  const int bc = t & 7;
  const int bh = bc >> 2;
  const int bq4 = bc & 3;
  const int* adjL = adj + ((size_t)b * kN + row0 + brow) * kN + bh * 1024 + bq4 * 8;
  uint4 qcA = {}, qcB = {}, qnA = {}, qnB = {};
  if (PACK) {
    const uint4 a0 = *(const uint4*)(adjL);
    const uint4 a1 = *(const uint4*)(adjL + 4);
    ((unsigned char*)blw)[(brow * 65 + bh * 32) * 4 + bq4] = (unsigned char)pack8(a0, a1);
    qcA = *(const uint4*)(adjL + 32);
    qcB = *(const uint4*)(adjL + 36);
  } else {
#pragma unroll
    for (int ii = 0; ii < 8; ++ii) {
      const int idx = ii * 256 + t;
      const int rr2 = idx >> 6, wj = idx & 63;
      blw[rr2 * 65 + wj] = bits[((size_t)b * kN + row0 + rr2) * 64 + wj];
    }
  }

  const float Ri = Rr[(size_t)b * kN + row0 + rloc];
  __syncthreads();

  f32x4 acc0 = {0.f, 0.f, 0.f, 0.f}, acc1 = {0.f, 0.f, 0.f, 0.f};
  f32x4 acc2 = {0.f, 0.f, 0.f, 0.f}, acc3 = {0.f, 0.f, 0.f, 0.f};
  f32x4 accz = {0.f, 0.f, 0.f, 0.f};
  s16x8 ones;
#pragma unroll
  for (int e = 0; e < 8; ++e) ones[e] = (r == 0) ? (short)0x3F80 : (short)0;

  for (int jt = 0; jt < 32; ++jt) {
    // issue loads for step jt+2
    if (jt < 30) {
      hn0 = *(const uint4*)(hTb + (size_t)(jt + 2) * 2048 + t * 8);
      hn1 = *(const uint4*)(hTb + (size_t)(32 + jt + 2) * 2048 + t * 8);
      if (PACK) {
        qnA = *(const uint4*)(adjL + (size_t)(jt + 2) * 32);
        qnB = *(const uint4*)(adjL + (size_t)(jt + 2) * 32 + 4);
      }
    }
    // publish step jt+1 (loaded one iter ago); conflict-free contiguous writes
    if (jt < 31) {
      const int buf = (jt + 1) & 1;
      *(uint4*)(hbase + (buf * 2 + 0) * 2048 + t * 8) = hc0;
      *(uint4*)(hbase + (buf * 2 + 1) * 2048 + t * 8) = hc1;
      if (PACK)
        ((unsigned char*)blw)[(brow * 65 + bh * 32 + jt + 1) * 4 + bq4] =
            (unsigned char)pack8(qcA, qcB);
    }

    // consume step jt from LDS
    const unsigned int bw = blw[rloc * 65 + hf2 * 32 + jt];
    const unsigned int byt = (bw >> (g * 8)) & 0xffu;
    const unsigned int* uvp = uvl + hf2 * 1024 + jt * 32 + g * 8;
    const uint4 ua = *(const uint4*)uvp;
    const uint4 ub = *(const uint4*)(uvp + 4);
    union { s16x8 v; unsigned int w[4]; } afu;
    {
      const unsigned int uvw[8] = {ua.x, ua.y, ua.z, ua.w, ub.x, ub.y, ub.z, ub.w};
#pragma unroll
      for (int p = 0; p < 4; ++p) {
        unsigned int ulb = uvw[2 * p] & 0xFFFF0000u, vlb = uvw[2 * p] << 16;
        unsigned int uhb = uvw[2 * p + 1] & 0xFFFF0000u, vhb = uvw[2 * p + 1] << 16;
        float ulf, vlf, uhf, vhf;
        __builtin_memcpy(&ulf, &ulb, 4); __builtin_memcpy(&vlf, &vlb, 4);
        __builtin_memcpy(&uhf, &uhb, 4); __builtin_memcpy(&vhf, &vhb, 4);
        const float vall = fmaxf(ulf, Ri * vlf);
        const float valh = fmaxf(uhf, Ri * vhf);
        unsigned int lbits, hbits;
        __builtin_memcpy(&lbits, &vall, 4); __builtin_memcpy(&hbits, &valh, 4);
        lbits = (byt & (1u << (2 * p))) ? lbits : 0u;
        hbits = (byt & (1u << (2 * p + 1))) ? hbits : 0u;
        afu.w[p] = (hbits & 0xFFFF0000u) | (lbits >> 16);
      }
    }
    const unsigned short* cur = hbase + ((jt & 1) * 2 + hf2) * 2048 + r * 32 + g * 8;
    const s16x8 f0 = *(const s16x8*)(cur);
    const s16x8 f1 = *(const s16x8*)(cur + 512);
    const s16x8 f2 = *(const s16x8*)(cur + 1024);
    const s16x8 f3 = *(const s16x8*)(cur + 1536);

    acc0 = __builtin_amdgcn_mfma_f32_16x16x32_bf16(afu.v, f0, acc0, 0, 0, 0);
    acc1 = __builtin_amdgcn_mfma_f32_16x16x32_bf16(afu.v, f1, acc1, 0, 0, 0);
    acc2 = __builtin_amdgcn_mfma_f32_16x16x32_bf16(afu.v, f2, acc2, 0, 0, 0);
    acc3 = __builtin_amdgcn_mfma_f32_16x16x32_bf16(afu.v, f3, acc3, 0, 0, 0);
    accz = __builtin_amdgcn_mfma_f32_16x16x32_bf16(afu.v, ones, accz, 0, 0, 0);

    // raw barrier: wait LDS ops only; global prefetch stays in flight (T4)
    asm volatile("s_waitcnt lgkmcnt(0)" ::: "memory");
    __builtin_amdgcn_s_barrier();
    hc0 = hn0; hc1 = hn1;
    if (PACK) { qcA = qnA; qcB = qnB; }
  }

  // ---- epilogue: in-block combine of the two j-halves ----
  float* psumF = (float*)(smem + 16512);          // [2][16][66]
  float* zsumF = (float*)(smem + 16512 + 8448);   // [32]
  if (hf2 == 1) {
#pragma unroll
    for (int q = 0; q < 4; ++q) {
      const int lrow = rt * 16 + g * 4 + q;
      psumF[lrow * 66 + r + 0]  = acc0[q];
      psumF[lrow * 66 + r + 16] = acc1[q];
      psumF[lrow * 66 + r + 32] = acc2[q];
      psumF[lrow * 66 + r + 48] = acc3[q];
      if (r == 0) zsumF[lrow] = accz[q];
    }
  }
  __syncthreads();
  float* lhFF = (float*)smem;  // TAIL: final h2 rows [32][65]
  if (hf2 == 0) {
#pragma unroll
    for (int q = 0; q < 4; ++q) {
      const int lrow = rt * 16 + g * 4 + q;
      const float zq = __shfl(accz[q], (l & 48)) + zsumF[lrow];
      const float inv = (zq > 0.0f) ? 1.0f / zq : 0.0f;
      const size_t rowg = (size_t)b * kN + row0 + lrow;
      const float mk = mask[rowg];
      const float* hrp = hres + rowg * kH;
      const float o0 = eluf(fmaf(acc0[q] + psumF[lrow * 66 + r + 0],  inv, hrp[r + 0]))  * mk;
      const float o1 = eluf(fmaf(acc1[q] + psumF[lrow * 66 + r + 16], inv, hrp[r + 16])) * mk;
      const float o2 = eluf(fmaf(acc2[q] + psumF[lrow * 66 + r + 32], inv, hrp[r + 32])) * mk;
      const float o3 = eluf(fmaf(acc3[q] + psumF[lrow * 66 + r + 48], inv, hrp[r + 48])) * mk;
      if (TAIL) {
        lhFF[lrow * 65 + r + 0]  = o0;
        lhFF[lrow * 65 + r + 16] = o1;
        lhFF[lrow * 65 + r + 32] = o2;
        lhFF[lrow * 65 + r + 48] = o3;
      } else {
        hout[rowg * kH + r + 0]  = o0;
        hout[rowg * kH + r + 16] = o1;
        hout[rowg * kH + r + 32] = o2;
        hout[rowg * kH + r + 48] = o3;
      }
    }
  }
  if (PACK) {
#pragma unroll
    for (int ii = 0; ii < 8; ++ii) {
      const int idx = ii * 256 + t;
      const int rr2 = idx >> 6, wj = idx & 63;
      bits[((size_t)b * kN + row0 + rr2) * 64 + wj] = blw[rr2 * 65 + wj];
    }
  }

  if (TAIL) {
    __syncthreads();
    const int ln = t & 31;
    const int grp = t >> 5;
#pragma unroll
    for (int rr2 = 0; rr2 < 4; ++rr2) {
      const int lrow = grp * 4 + rr2;
      float accA = ab1[ln];
#pragma unroll 8
      for (int m = 0; m < kH; ++m) accA = fmaf(lhFF[lrow * 65 + m], aw1[m * 32 + ln], accA);
      float p = eluf(accA) * aw2[ln];
#pragma unroll
      for (int o = 16; o; o >>= 1) p += __shfl_xor(p, o, 32);
      if (ln == 0) logits[(size_t)b * kN + row0 + lrow] = p + ab2[0];
    }
    float cs = 0.0f;
    const int kcol = t & 63;
    const int seg = t >> 6;
#pragma unroll
    for (int ii = 0; ii < 8; ++ii) cs += lhFF[(seg * 8 + ii) * 65 + kcol];
    float* csF = (float*)(smem + 16512 + 8704);
    csF[seg * 64 + kcol] = cs;
    __syncthreads();
    if (t < 64) atomicAdd(&sumh[b * 64 + t], csF[t] + csF[64 + t] + csF[128 + t] + csF[192 + t]);
  }
}

// ---------------------------------------------------------------- critic head
__global__ __launch_bounds__(64) void k_critic2(
    const float* __restrict__ sumh, const float* __restrict__ mask,
    const float* __restrict__ cw1, const float* __restrict__ cb1,
    const float* __restrict__ cw2, const float* __restrict__ cb2,
    float* __restrict__ value) {
  __shared__ float lgh[64];
  const int b = blockIdx.x, t = threadIdx.x;
  float c = 0.0f;
#pragma unroll
  for (int ii = 0; ii < 32; ++ii) c += mask[(size_t)b * kN + t + 64 * ii];
#pragma unroll
  for (int off = 32; off; off >>= 1) c += __shfl_xor(c, off);
  lgh[t] = sumh[b * 64 + t] / fmaxf(c, 1.0f);
  __syncthreads();
  if (t < 32) {
    float acc = cb1[t];
#pragma unroll 8
    for (int m = 0; m < kH; ++m) acc = fmaf(lgh[m], cw1[m * 32 + t], acc);
    float p = eluf(acc) * cw2[t];
#pragma unroll
    for (int off = 16; off; off >>= 1) p += __shfl_xor(p, off, 32);
    if (t == 0) value[b] = p + cb2[0];
  }
}

// ----------------------------------------------------------------
extern "C" void kernel_launch(void* const* d_in, const int* in_sizes, int n_in,
                              void* d_out, int out_size, void* d_ws, size_t ws_size,
                              hipStream_t stream) {
  const float* x = (const float*)d_in[0];
  const int* adj = (const int*)d_in[1];
  const float* mask = (const float*)d_in[2];
  const float* W1 = (const float*)d_in[3];
  const float* asrc1 = (const float*)d_in[4];
  const float* adst1 = (const float*)d_in[5];
  const float* W2 = (const float*)d_in[6];
  const float* asrc2 = (const float*)d_in[7];
  const float* adst2 = (const float*)d_in[8];
  const float* aw1 = (const float*)d_in[9];
  const float* ab1 = (const float*)d_in[10];
  const float* aw2 = (const float*)d_in[11];
  const float* ab2 = (const float*)d_in[12];
  const float* cw1 = (const float*)d_in[13];
  const float* cb1 = (const float*)d_in[14];
  const float* cw2 = (const float*)d_in[15];
  const float* cb2 = (const float*)d_in[16];
  float* logits = (float*)d_out;
  float* value = (float*)d_out + kB * kN;

  char* ws = (char*)d_ws;
  size_t off = 0;
  auto take = [&](size_t bytes) {
    char* p = ws + off;
    off = (off + bytes + 255) & ~(size_t)255;
    return p;
  };
  unsigned int* bits = (unsigned int*)take((size_t)kB * kN * (kN / 8));
  float* hA = (float*)take((size_t)kB * kN * kH * 4);
  float* hB = (float*)take((size_t)kB * kN * kH * 4);
  unsigned short* hT = (unsigned short*)take((size_t)kB * kN * kH * 2);
  unsigned int* uvpk = (unsigned int*)take((size_t)kB * kN * 4);
  float* RArr = (float*)take((size_t)kB * kN * 4);
  float* sumh = (float*)take(kB * kH * 4);

  // layer 1: embed -> attn (JIT-packs adj, writes bits + final h1 -> hB)
  k_embed<<<kB * kN / 64, 256, 0, stream>>>(x, W1, asrc1, adst1, mask, hA, hT, uvpk, RArr, sumh);
  k_attn<true, false><<<kB * 64, 256, 0, stream>>>(adj, bits, hT, uvpk, RArr, hA, mask, hB,
                                                   aw1, ab1, aw2, ab2, logits, sumh);

  // layer 2: embed (reads hB) -> attn (tail-fused: actor + column sums)
  k_embed2<<<kB * kN / 64, 256, 0, stream>>>(hB, W2, asrc2, adst2, mask, hA, hT, uvpk, RArr);
  k_attn<false, true><<<kB * 64, 256, 0, stream>>>(adj, bits, hT, uvpk, RArr, hA, mask, hB,
                                                   aw1, ab1, aw2, ab2, logits, sumh);

  // critic
  k_critic2<<<kB, 64, 0, stream>>>(sumh, mask, cw1, cb1, cw2, cb2, value);
}